// Round 1
// baseline (550.918 us; speedup 1.0000x reference)
//
#include <hip/hip_runtime.h>
#include <cfloat>

// Problem constants
#define BB 64          // batch
#define CC 2048        // x channels
#define AR 2048        // x_art channels
#define DD 4096        // CC + AR
#define VV 256         // views
#define FF 4096        // hidden
#define OO 1000        // out channels

// ---------------------------------------------------------------------------
// Kernel 1: ragged max-pool over views, writes pooled TRANSPOSED [D][64].
// One wave per (b, d) row; lane i covers float4 at v = 4*i (coalesced).
// Only reads v < len -> ~half the 256 MiB on average.
// ---------------------------------------------------------------------------
__global__ __launch_bounds__(256) void pool_kernel(
    const float* __restrict__ x, const float* __restrict__ xart,
    const int* __restrict__ ll, float* __restrict__ pooledT)
{
    int wave = threadIdx.x >> 6;
    int lane = threadIdx.x & 63;
    int row  = blockIdx.x * 4 + wave;          // [0, BB*DD)
    int b = row >> 12;                         // / 4096
    int d = row & 4095;
    int len = ll[b];
    if (len < 1) len = 1;
    const float* src = (d < CC) ? (x    + ((size_t)b * CC + d)        * VV)
                                : (xart + ((size_t)b * AR + (d - CC)) * VV);
    float m = -FLT_MAX;
    int v0 = lane * 4;
    if (v0 < len) {
        float4 v = *(const float4*)(src + v0);
        m = v.x;
        if (v0 + 1 < len) m = fmaxf(m, v.y);
        if (v0 + 2 < len) m = fmaxf(m, v.z);
        if (v0 + 3 < len) m = fmaxf(m, v.w);
    }
    #pragma unroll
    for (int off = 32; off > 0; off >>= 1)
        m = fmaxf(m, __shfl_xor(m, off, 64));
    if (lane == 0) pooledT[(size_t)d * 64 + b] = m;
}

// ---------------------------------------------------------------------------
// Kernel 2: split-K GEMM partial.  C_part[chunk][b][f] = sum_{k in chunk} P[k][b]*W[k][f]
// P is [K][64] (transposed activations), W is [K][F] row-major.
// Block: 256 threads, tile 64 b x 128 f, K-chunk = kchunk (16-row LDS stages).
// Thread (tx = t&15, ty = t>>4): b = ty*4+i, f = f0 + tx*4+j (j<4) or f0+64+tx*4+(j-4).
// ---------------------------------------------------------------------------
__global__ __launch_bounds__(256) void gemm_partial(
    const float* __restrict__ P, const float* __restrict__ W,
    float* __restrict__ part, int K, int F, int kchunk)
{
    __shared__ float lds_p[16][64];
    __shared__ float lds_w[16][128];
    int t  = threadIdx.x;
    int tx = t & 15, ty = t >> 4;
    int f0 = blockIdx.x * 128;
    int k0 = blockIdx.y * kchunk;
    int stages = kchunk >> 4;
    bool full = (f0 + 128 <= F);

    float acc[4][8];
    #pragma unroll
    for (int i = 0; i < 4; ++i)
        #pragma unroll
        for (int j = 0; j < 8; ++j) acc[i][j] = 0.f;

    for (int s = 0; s < stages; ++s) {
        int k = k0 + s * 16 + ty;              // ty doubles as stage row 0..15
        float4 pv = *(const float4*)(P + (size_t)k * 64 + tx * 4);
        const float* wr = W + (size_t)k * F + f0;
        float4 wv0, wv1;
        if (full) {
            wv0 = *(const float4*)(wr + tx * 4);
            wv1 = *(const float4*)(wr + 64 + tx * 4);
        } else {
            float tmp[8];
            #pragma unroll
            for (int e = 0; e < 8; ++e) {
                int c = (e < 4) ? (tx * 4 + e) : (64 + tx * 4 + (e - 4));
                tmp[e] = (f0 + c < F) ? wr[c] : 0.f;
            }
            wv0 = make_float4(tmp[0], tmp[1], tmp[2], tmp[3]);
            wv1 = make_float4(tmp[4], tmp[5], tmp[6], tmp[7]);
        }
        __syncthreads();
        *(float4*)&lds_p[ty][tx * 4]      = pv;
        *(float4*)&lds_w[ty][tx * 4]      = wv0;
        *(float4*)&lds_w[ty][64 + tx * 4] = wv1;
        __syncthreads();
        #pragma unroll
        for (int kk = 0; kk < 16; ++kk) {
            float4 p4 = *(const float4*)&lds_p[kk][ty * 4];
            float4 wa = *(const float4*)&lds_w[kk][tx * 4];
            float4 wb = *(const float4*)&lds_w[kk][64 + tx * 4];
            #pragma unroll
            for (int i = 0; i < 4; ++i) {
                float pi = (i == 0) ? p4.x : (i == 1) ? p4.y : (i == 2) ? p4.z : p4.w;
                acc[i][0] += pi * wa.x;  acc[i][1] += pi * wa.y;
                acc[i][2] += pi * wa.z;  acc[i][3] += pi * wa.w;
                acc[i][4] += pi * wb.x;  acc[i][5] += pi * wb.y;
                acc[i][6] += pi * wb.z;  acc[i][7] += pi * wb.w;
            }
        }
    }

    float* dst = part + (size_t)(blockIdx.y * 64) * F;
    #pragma unroll
    for (int i = 0; i < 4; ++i) {
        int brow = ty * 4 + i;
        float* r = dst + (size_t)brow * F + f0;
        if (full) {
            *(float4*)(r + tx * 4)      = make_float4(acc[i][0], acc[i][1], acc[i][2], acc[i][3]);
            *(float4*)(r + 64 + tx * 4) = make_float4(acc[i][4], acc[i][5], acc[i][6], acc[i][7]);
        } else {
            #pragma unroll
            for (int j = 0; j < 8; ++j) {
                int c = (j < 4) ? (tx * 4 + j) : (64 + tx * 4 + (j - 4));
                if (f0 + c < F) r[c] = acc[i][j];
            }
        }
    }
}

// ---------------------------------------------------------------------------
// Kernel 3: reduce split-K partials + bias + ReLU, output TRANSPOSED [F][64]
// (so the next GEMM's staging loads stay coalesced). LDS transpose with
// stride-65 padding (bank = (b+f)%32 -> conflict-free).
// ---------------------------------------------------------------------------
__global__ __launch_bounds__(256) void reduce_bias_relu_T(
    const float* __restrict__ part, const float* __restrict__ bias,
    float* __restrict__ outT, int nchunk, int F)
{
    __shared__ float lds[64 * 65];
    int t  = threadIdx.x;
    int f0 = blockIdx.x * 64;
    for (int r = 0; r < 16; ++r) {
        int idx = r * 256 + t;
        int b = idx >> 6, f = idx & 63;
        float v = bias[f0 + f];
        for (int c = 0; c < nchunk; ++c)
            v += part[(size_t)(c * 64 + b) * F + f0 + f];
        v = fmaxf(v, 0.f);
        lds[b * 65 + f] = v;
    }
    __syncthreads();
    for (int r = 0; r < 16; ++r) {
        int idx = r * 256 + t;
        int f = idx >> 6, b = idx & 63;
        outT[(size_t)(f0 + f) * 64 + b] = lds[b * 65 + f];
    }
}

// ---------------------------------------------------------------------------
// Kernel 4: final reduce + bias (no ReLU), writes d_out [64][1000].
// ---------------------------------------------------------------------------
__global__ __launch_bounds__(256) void reduce_out_kernel(
    const float* __restrict__ part, const float* __restrict__ bias,
    float* __restrict__ out, int nchunk)
{
    int idx = blockIdx.x * 256 + threadIdx.x;
    if (idx >= BB * OO) return;
    int b = idx / OO, f = idx - b * OO;
    float v = bias[f];
    for (int c = 0; c < nchunk; ++c)
        v += part[(size_t)(c * 64 + b) * OO + f];
    out[idx] = v;
}

// ---------------------------------------------------------------------------
extern "C" void kernel_launch(void* const* d_in, const int* in_sizes, int n_in,
                              void* d_out, int out_size, void* d_ws, size_t ws_size,
                              hipStream_t stream) {
    const float* x    = (const float*)d_in[0];
    const float* xart = (const float*)d_in[1];
    const int*   ll   = (const int*)d_in[2];
    const float* w1   = (const float*)d_in[3];
    const float* b1   = (const float*)d_in[4];
    const float* w2   = (const float*)d_in[5];
    const float* b2   = (const float*)d_in[6];
    const float* w3   = (const float*)d_in[7];
    const float* b3   = (const float*)d_in[8];
    float* out = (float*)d_out;

    // workspace layout (ws is re-poisoned before every launch; everything we
    // read is written first): pooledT 1MiB | h1T 1MiB | h2T 1MiB | part 8MiB
    float* pooledT = (float*)d_ws;
    float* h1T     = pooledT + (size_t)DD * 64;
    float* h2T     = h1T     + (size_t)FF * 64;
    float* part    = h2T     + (size_t)FF * 64;

    // 1) ragged max-pool -> pooledT [4096][64]
    pool_kernel<<<(BB * DD) / 4, 256, 0, stream>>>(x, xart, ll, pooledT);

    // 2) h1 = relu(pooled @ w1 + b1): split-K 8 chunks of 512, 32 f-tiles
    gemm_partial<<<dim3(32, 8), 256, 0, stream>>>(pooledT, w1, part, DD, FF, 512);
    reduce_bias_relu_T<<<FF / 64, 256, 0, stream>>>(part, b1, h1T, 8, FF);

    // 3) h2 = relu(h1 @ w2 + b2)
    gemm_partial<<<dim3(32, 8), 256, 0, stream>>>(h1T, w2, part, FF, FF, 512);
    reduce_bias_relu_T<<<FF / 64, 256, 0, stream>>>(part, b2, h2T, 8, FF);

    // 4) out = h2 @ w3 + b3: 8 f-tiles (last partial), 32 chunks of 128
    gemm_partial<<<dim3(8, 32), 256, 0, stream>>>(h2T, w3, part, FF, OO, 128);
    reduce_out_kernel<<<(BB * OO + 255) / 256, 256, 0, stream>>>(part, b3, out, 32);
}

// Round 2
// 420.936 us; speedup vs baseline: 1.3088x; 1.3088x over previous
//
#include <hip/hip_runtime.h>
#include <cfloat>

// Problem constants
#define BB 64          // batch
#define CC 2048        // x channels
#define AR 2048        // x_art channels
#define DD 4096        // CC + AR
#define VV 256         // views
#define FF 4096        // hidden
#define OO 1000        // out channels

// ---------------------------------------------------------------------------
// Kernel 1: ragged max-pool over views -> pooled TRANSPOSED [D][64].
// 8192 waves, each handles 32 consecutive (b,d) rows, 4 rows per iteration
// (4 independent float4 loads in flight). b and len hoisted per wave
// (32 rows never straddle a batch or the CC/ART boundary: both are
// multiples of 32). Lane i covers v = 4i..4i+3 (one float4 spans the row).
// ---------------------------------------------------------------------------
__global__ __launch_bounds__(256) void pool_kernel(
    const float* __restrict__ x, const float* __restrict__ xart,
    const int* __restrict__ ll, float* __restrict__ pooledT)
{
    int waveId = (blockIdx.x * 256 + threadIdx.x) >> 6;   // 0..8191
    int lane   = threadIdx.x & 63;
    int row0   = waveId * 32;                             // 32 rows per wave
    int b  = row0 >> 12;
    int d0 = row0 & 4095;
    int len = ll[b];
    if (len < 1) len = 1;
    const float* base = (d0 < CC)
        ? (x    + ((size_t)b * CC + d0)        * VV)
        : (xart + ((size_t)b * AR + (d0 - CC)) * VV);
    int v0  = lane * 4;
    int rem = len - v0;           // >0 means lane active; same for all 32 rows

    for (int r = 0; r < 32; r += 4) {
        const float* s = base + (size_t)r * VV;
        float m0 = -FLT_MAX, m1 = -FLT_MAX, m2 = -FLT_MAX, m3 = -FLT_MAX;
        if (rem > 0) {
            float4 a0 = *(const float4*)(s + v0);
            float4 a1 = *(const float4*)(s + VV + v0);
            float4 a2 = *(const float4*)(s + 2 * VV + v0);
            float4 a3 = *(const float4*)(s + 3 * VV + v0);
            m0 = a0.x; m1 = a1.x; m2 = a2.x; m3 = a3.x;
            if (rem > 1) { m0 = fmaxf(m0, a0.y); m1 = fmaxf(m1, a1.y);
                           m2 = fmaxf(m2, a2.y); m3 = fmaxf(m3, a3.y); }
            if (rem > 2) { m0 = fmaxf(m0, a0.z); m1 = fmaxf(m1, a1.z);
                           m2 = fmaxf(m2, a2.z); m3 = fmaxf(m3, a3.z); }
            if (rem > 3) { m0 = fmaxf(m0, a0.w); m1 = fmaxf(m1, a1.w);
                           m2 = fmaxf(m2, a2.w); m3 = fmaxf(m3, a3.w); }
        }
        #pragma unroll
        for (int off = 32; off > 0; off >>= 1) {
            m0 = fmaxf(m0, __shfl_xor(m0, off, 64));
            m1 = fmaxf(m1, __shfl_xor(m1, off, 64));
            m2 = fmaxf(m2, __shfl_xor(m2, off, 64));
            m3 = fmaxf(m3, __shfl_xor(m3, off, 64));
        }
        // every lane now holds the row max; lanes 0..3 write rows r..r+3
        float wv = m0;
        if (lane == 1) wv = m1;
        else if (lane == 2) wv = m2;
        else if (lane == 3) wv = m3;
        if (lane < 4)
            pooledT[(size_t)(d0 + r + lane) * 64 + b] = wv;
    }
}

// ---------------------------------------------------------------------------
// Kernel 2: split-K GEMM partial with register prefetch of the next stage.
// part[chunk][b][f] = sum_{k in chunk} P[k][b] * W[k][f]
// P is [K][64] (transposed acts), W is [K][F] row-major.
// Block 256 thr, tile 64b x 128f, stages of 16 K-rows; next stage's global
// loads are issued right after the LDS store so they overlap the 16-kk
// compute loop (~1024 cyc) -- latency fully hidden at >=2 waves/SIMD.
// F-tail (F=1000): first 64-wide half always valid (f0+63 <= 959), only
// the second half is predicated.
// ---------------------------------------------------------------------------
__global__ __launch_bounds__(256) void gemm_partial(
    const float* __restrict__ P, const float* __restrict__ W,
    float* __restrict__ part, int F, int kchunk)
{
    __shared__ float lds_p[16][64];
    __shared__ float lds_w[16][128];
    int t  = threadIdx.x;
    int tx = t & 15, ty = t >> 4;
    int f0 = blockIdx.x * 128;
    int k0 = blockIdx.y * kchunk;
    int stages = kchunk >> 4;
    int c1 = f0 + tx * 4;          // always fully in-bounds
    int c2 = f0 + 64 + tx * 4;     // may be OOB on the tail tile
    bool v2 = (c2 + 3 < F) || (c2 + 4 == F);

    float acc[4][8];
    #pragma unroll
    for (int i = 0; i < 4; ++i)
        #pragma unroll
        for (int j = 0; j < 8; ++j) acc[i][j] = 0.f;

    // prefetch stage 0
    int k = k0 + ty;
    float4 pv  = *(const float4*)(P + (size_t)k * 64 + tx * 4);
    const float* wr = W + (size_t)k * F;
    float4 wv0 = *(const float4*)(wr + c1);
    float4 wv1;
    if (v2) wv1 = *(const float4*)(wr + c2);
    else {
        wv1.x = (c2     < F) ? wr[c2]     : 0.f;
        wv1.y = (c2 + 1 < F) ? wr[c2 + 1] : 0.f;
        wv1.z = (c2 + 2 < F) ? wr[c2 + 2] : 0.f;
        wv1.w = (c2 + 3 < F) ? wr[c2 + 3] : 0.f;
    }

    for (int s = 0; s < stages; ++s) {
        __syncthreads();
        *(float4*)&lds_p[ty][tx * 4]      = pv;
        *(float4*)&lds_w[ty][tx * 4]      = wv0;
        *(float4*)&lds_w[ty][64 + tx * 4] = wv1;
        __syncthreads();
        if (s + 1 < stages) {                       // prefetch stage s+1
            int kn = k0 + (s + 1) * 16 + ty;
            pv = *(const float4*)(P + (size_t)kn * 64 + tx * 4);
            const float* wrn = W + (size_t)kn * F;
            wv0 = *(const float4*)(wrn + c1);
            if (v2) wv1 = *(const float4*)(wrn + c2);
            else {
                wv1.x = (c2     < F) ? wrn[c2]     : 0.f;
                wv1.y = (c2 + 1 < F) ? wrn[c2 + 1] : 0.f;
                wv1.z = (c2 + 2 < F) ? wrn[c2 + 2] : 0.f;
                wv1.w = (c2 + 3 < F) ? wrn[c2 + 3] : 0.f;
            }
        }
        #pragma unroll
        for (int kk = 0; kk < 16; ++kk) {
            float4 p4 = *(const float4*)&lds_p[kk][ty * 4];
            float4 wa = *(const float4*)&lds_w[kk][tx * 4];
            float4 wb = *(const float4*)&lds_w[kk][64 + tx * 4];
            #pragma unroll
            for (int i = 0; i < 4; ++i) {
                float pi = (i == 0) ? p4.x : (i == 1) ? p4.y : (i == 2) ? p4.z : p4.w;
                acc[i][0] += pi * wa.x;  acc[i][1] += pi * wa.y;
                acc[i][2] += pi * wa.z;  acc[i][3] += pi * wa.w;
                acc[i][4] += pi * wb.x;  acc[i][5] += pi * wb.y;
                acc[i][6] += pi * wb.z;  acc[i][7] += pi * wb.w;
            }
        }
    }

    float* dst = part + (size_t)(blockIdx.y * 64) * F;
    #pragma unroll
    for (int i = 0; i < 4; ++i) {
        float* r = dst + (size_t)(ty * 4 + i) * F;
        *(float4*)(r + c1) = make_float4(acc[i][0], acc[i][1], acc[i][2], acc[i][3]);
        if (v2)
            *(float4*)(r + c2) = make_float4(acc[i][4], acc[i][5], acc[i][6], acc[i][7]);
        else {
            if (c2     < F) r[c2]     = acc[i][4];
            if (c2 + 1 < F) r[c2 + 1] = acc[i][5];
            if (c2 + 2 < F) r[c2 + 2] = acc[i][6];
            if (c2 + 3 < F) r[c2 + 3] = acc[i][7];
        }
    }
}

// ---------------------------------------------------------------------------
// Kernel 3: reduce split-K partials + bias + ReLU -> TRANSPOSED [F][64].
// 16-wide f tiles (256 blocks -> all CUs busy); chunk-outer loop with a
// 4-register accumulator gives 4 independent loads per chunk step.
// LDS transpose with stride-17 padding (odd stride -> 2-way max, free).
// ---------------------------------------------------------------------------
__global__ __launch_bounds__(256) void reduce_bias_relu_T(
    const float* __restrict__ part, const float* __restrict__ bias,
    float* __restrict__ outT, int nchunk, int F)
{
    __shared__ float lds[64 * 17];
    int t  = threadIdx.x;
    int f0 = blockIdx.x * 16;
    int fl = t & 15;          // local f
    int ty = t >> 4;          // 0..15
    float bv = bias[f0 + fl];
    float acc[4];
    #pragma unroll
    for (int j = 0; j < 4; ++j) acc[j] = bv;
    for (int c = 0; c < nchunk; ++c) {
        const float* p = part + ((size_t)c * 64) * F + f0 + fl;
        #pragma unroll
        for (int j = 0; j < 4; ++j) {
            int b = j * 16 + ty;
            acc[j] += p[(size_t)b * F];
        }
    }
    #pragma unroll
    for (int j = 0; j < 4; ++j) {
        int b = j * 16 + ty;
        lds[b * 17 + fl] = fmaxf(acc[j], 0.f);
    }
    __syncthreads();
    #pragma unroll
    for (int j = 0; j < 4; ++j) {
        int idx = j * 256 + t;
        int f = idx >> 6;     // 0..15
        int b = idx & 63;
        outT[(size_t)(f0 + f) * 64 + b] = lds[b * 17 + f];
    }
}

// ---------------------------------------------------------------------------
// Kernel 4: final reduce + bias (no ReLU) -> d_out [64][1000].
// One output per thread; unroll-8 keeps 8 independent loads in flight.
// ---------------------------------------------------------------------------
__global__ __launch_bounds__(256) void reduce_out_kernel(
    const float* __restrict__ part, const float* __restrict__ bias,
    float* __restrict__ out, int nchunk)
{
    int idx = blockIdx.x * 256 + threadIdx.x;
    if (idx >= BB * OO) return;
    int b = idx / OO, f = idx - b * OO;
    float v = bias[f];
    const float* p = part + (size_t)b * OO + f;
    #pragma unroll 8
    for (int c = 0; c < nchunk; ++c)
        v += p[(size_t)c * 64 * OO];
    out[idx] = v;
}

// ---------------------------------------------------------------------------
extern "C" void kernel_launch(void* const* d_in, const int* in_sizes, int n_in,
                              void* d_out, int out_size, void* d_ws, size_t ws_size,
                              hipStream_t stream) {
    const float* x    = (const float*)d_in[0];
    const float* xart = (const float*)d_in[1];
    const int*   ll   = (const int*)d_in[2];
    const float* w1   = (const float*)d_in[3];
    const float* b1   = (const float*)d_in[4];
    const float* w2   = (const float*)d_in[5];
    const float* b2   = (const float*)d_in[6];
    const float* w3   = (const float*)d_in[7];
    const float* b3   = (const float*)d_in[8];
    float* out = (float*)d_out;

    // workspace: pooledT 1MiB | h1T 1MiB | h2T 1MiB | part (split-K partials)
    float* pooledT = (float*)d_ws;
    float* h1T     = pooledT + (size_t)DD * 64;
    float* h2T     = h1T     + (size_t)FF * 64;
    float* part    = h2T     + (size_t)FF * 64;

    // adapt split-K factor to available workspace (deterministic per session)
    size_t actBytes = (size_t)(DD + FF + FF) * 64 * sizeof(float);   // 3 MiB
    size_t avail    = (ws_size > actBytes) ? ws_size - actBytes : 0;
    size_t plane1   = (size_t)64 * FF * sizeof(float);               // 1 MiB
    int nk1 = 8;
    if (avail >= 32 * plane1)      nk1 = 32;   // 1024 blocks: 4 blocks/CU
    else if (avail >= 16 * plane1) nk1 = 16;
    size_t plane3 = (size_t)64 * OO * sizeof(float);                 // 250 KiB
    int nk3 = (avail >= 64 * plane3) ? 64 : 32;
    int kchunk1 = DD / nk1;
    int kchunk3 = FF / nk3;

    // 1) ragged max-pool -> pooledT [4096][64]
    pool_kernel<<<2048, 256, 0, stream>>>(x, xart, ll, pooledT);

    // 2) h1 = relu(pooled @ w1 + b1)
    gemm_partial<<<dim3(32, nk1), 256, 0, stream>>>(pooledT, w1, part, FF, kchunk1);
    reduce_bias_relu_T<<<FF / 16, 256, 0, stream>>>(part, b1, h1T, nk1, FF);

    // 3) h2 = relu(h1 @ w2 + b2)
    gemm_partial<<<dim3(32, nk1), 256, 0, stream>>>(h1T, w2, part, FF, kchunk1);
    reduce_bias_relu_T<<<FF / 16, 256, 0, stream>>>(part, b2, h2T, nk1, FF);

    // 4) out = h2 @ w3 + b3
    gemm_partial<<<dim3(8, nk3), 256, 0, stream>>>(h2T, w3, part, OO, kchunk3);
    reduce_out_kernel<<<(BB * OO + 255) / 256, 256, 0, stream>>>(part, b3, out, nk3);
}